// Round 11
// baseline (106.537 us; speedup 1.0000x reference)
//
#include <hip/hip_runtime.h>
#include <hip/hip_bf16.h>

typedef __attribute__((ext_vector_type(8))) _Float16 half8;
typedef __attribute__((ext_vector_type(4))) _Float16 half4;
typedef __attribute__((ext_vector_type(4))) float f32x4;

#define MFMAH(a,b,c) __builtin_amdgcn_mfma_f32_16x16x32_f16(a,b,c,0,0,0)

#define LOG2_10K_64 0.2076205059304595f
#define INV2PI 0.15915494309189535f

// ---------------------------------------------------------------------------
// Prep: W1 -> W1t[n][k] f16; Wq/Wk/Wv -> transposed f16; Pe[2048][2048] f16
// pos-enc table. Grid: 64 transpose + 192 qkv + 1024 Pe blocks.
// ---------------------------------------------------------------------------
__global__ __launch_bounds__(256) void k_prep(const float* __restrict__ W1,
                                              const float* __restrict__ Wq,
                                              const float* __restrict__ Wk,
                                              const float* __restrict__ Wv,
                                              _Float16* __restrict__ W1t,
                                              _Float16* __restrict__ Wqkvt,
                                              _Float16* __restrict__ Pe) {
  const int bid = blockIdx.x, tid = threadIdx.x;
  if (bid < 64) {
    __shared__ float Tl[64][65];
    const int kt0 = (bid >> 1) * 64, nt0 = (bid & 1) * 64;
    const int row = tid >> 2, c0 = (tid & 3) * 16;
#pragma unroll
    for (int e = 0; e < 16; e += 4) {
      float4 f = *(const float4*)(W1 + (size_t)(kt0 + row) * 128 + nt0 + c0 + e);
      Tl[row][c0 + e] = f.x; Tl[row][c0 + e + 1] = f.y;
      Tl[row][c0 + e + 2] = f.z; Tl[row][c0 + e + 3] = f.w;
    }
    __syncthreads();
    const int nrow = tid >> 2, kc0 = (tid & 3) * 16;
    _Float16* wp = W1t + (size_t)(nt0 + nrow) * 2048 + kt0 + kc0;
#pragma unroll
    for (int e = 0; e < 16; ++e) wp[e] = (_Float16)Tl[kc0 + e][nrow];
  } else if (bid < 256) {
    int r = (bid - 64) * 256 + tid;
    if (r < 3 * 16384) {
      int m = r >> 14, e = r & 16383;
      int n = e >> 7, k = e & 127;
      const float* W = (m == 0) ? Wq : (m == 1) ? Wk : Wv;
      Wqkvt[r] = (_Float16)W[k * 128 + n];
    }
  } else {
    const int g = (bid - 256) * 256 + tid;      // 0..262143
    const int s = g >> 7;
    const int j0 = (g & 127) * 16;
    const float sf = (float)s;
    half8 o0, o1;
#pragma unroll
    for (int p = 0; p < 8; ++p) {
      const int jh = (j0 >> 1) + p;
      float c = exp2f((float)jh * -LOG2_10K_64) * INV2PI;
      float r = __builtin_fmaf(sf, c, -rintf(sf * c));
      _Float16 sn = (_Float16)__builtin_amdgcn_sinf(r);
      _Float16 cs = (_Float16)__builtin_amdgcn_cosf(r);
      if (p < 4) { o0[2 * p] = sn; o0[2 * p + 1] = cs; }
      else       { o1[2 * (p - 4)] = sn; o1[2 * (p - 4) + 1] = cs; }
    }
    _Float16* dst = Pe + (size_t)s * 2048 + j0;
    *(half8*)dst = o0;
    *(half8*)(dst + 8) = o1;
  }
}

// ---------------------------------------------------------------------------
// GEMM1: h = relu((x + Pe) @ W1 + b1) -> f16.  [round-3 structure]
// BM=16, BN=128. 512 threads = 2 K-groups x 4 waves; group g covers K-half.
// Pad 68 (row stride 136B, conflict-free) -> 38.25 KB LDS -> 4 blocks/CU,
// 32 waves/CU. Pe table read replaces inline transcendental posenc.
// Grid 512.
// ---------------------------------------------------------------------------
__global__ __launch_bounds__(512) void k_gemm1(const float* __restrict__ x,
                                               const _Float16* __restrict__ W1t,
                                               const _Float16* __restrict__ Pe,
                                               const float* __restrict__ b1,
                                               _Float16* __restrict__ hbuf) {
  __shared__ __align__(16) char smem[39168];
  const int tid = threadIdx.x;
  const int g = tid >> 8;                 // K-group
  const int gtid = tid & 255;
  const int lane = tid & 63;
  const int wv = (tid >> 6) & 3;          // wave within group
  _Float16 (*Al)[68] = (_Float16(*)[68])(smem + g * 2176);             // [16][68]
  _Float16 (*Bl)[68] = (_Float16(*)[68])(smem + 4352 + g * 17408);     // [128][68]
  const int i0 = blockIdx.x * 16;
  const int arow = gtid >> 4, akc = (gtid & 15) * 4;
  const int brow = gtid >> 1, bk0 = (gtid & 1) * 32;
  const int grow = i0 + arow;
  const float* xrow = x + (size_t)grow * 2048;
  const _Float16* perow = Pe + (size_t)(grow & 2047) * 2048;
  const int fr = lane & 15, kg = (lane >> 4) * 8;
  f32x4 acc[2] = {};
  for (int it = 0; it < 16; ++it) {
    const int kt = g * 1024 + it * 64;
    // stage A = x + Pe -> f16
    {
      float4 f = *(const float4*)(xrow + kt + akc);
      half4 pv = *(const half4*)(perow + kt + akc);
      half4 av;
      av[0] = (_Float16)(f.x + (float)pv[0]);
      av[1] = (_Float16)(f.y + (float)pv[1]);
      av[2] = (_Float16)(f.z + (float)pv[2]);
      av[3] = (_Float16)(f.w + (float)pv[3]);
      *(half4*)&Al[arow][akc] = av;
    }
    // stage B from W1t (f16, n-major)
    {
      const _Float16* wp = W1t + (size_t)brow * 2048 + kt + bk0;
#pragma unroll
      for (int e = 0; e < 4; ++e)
        *(half8*)&Bl[brow][bk0 + e * 8] = *(const half8*)(wp + e * 8);
    }
    __syncthreads();
#pragma unroll
    for (int kk = 0; kk < 2; ++kk) {
      half8 a   = *(const half8*)&Al[fr][kk * 32 + kg];
      half8 b0  = *(const half8*)&Bl[wv * 32 + fr][kk * 32 + kg];
      half8 b1v = *(const half8*)&Bl[wv * 32 + 16 + fr][kk * 32 + kg];
      acc[0] = MFMAH(a, b0,  acc[0]);
      acc[1] = MFMAH(a, b1v, acc[1]);
    }
    __syncthreads();
  }
  // cross-group reduce through LDS (overlays staging region; all reads done)
  float (*Cred)[128] = (float(*)[128])smem;
  if (g == 1) {
#pragma unroll
    for (int n2 = 0; n2 < 2; ++n2)
#pragma unroll
      for (int r = 0; r < 4; ++r)
        Cred[(lane >> 4) * 4 + r][wv * 32 + n2 * 16 + fr] = acc[n2][r];
  }
  __syncthreads();
  if (g == 0) {
#pragma unroll
    for (int n2 = 0; n2 < 2; ++n2) {
      const int col = wv * 32 + n2 * 16 + fr;
      const float bv = b1[col];
#pragma unroll
      for (int r = 0; r < 4; ++r) {
        const int row_l = (lane >> 4) * 4 + r;
        float v = acc[n2][r] + Cred[row_l][col] + bv;
        v = v > 0.f ? v : 0.f;
        hbuf[(size_t)(i0 + row_l) * 128 + col] = (_Float16)v;
      }
    }
  }
}

// ---------------------------------------------------------------------------
// QKV: {Q,K,V} = h @ {Wq,Wk,Wv}, f16 out. BM=16, grid (512, 3).  [round 3]
// ---------------------------------------------------------------------------
__global__ __launch_bounds__(256) void k_qkv(const _Float16* __restrict__ hbuf,
                                             const _Float16* __restrict__ Wtb,
                                             _Float16* __restrict__ outb) {
  __shared__ _Float16 Al[16][136];
  __shared__ _Float16 Bl[128][136];
  const int tid = threadIdx.x;
  const int lane = tid & 63, wv = tid >> 6;
  const int i0 = blockIdx.x * 16;
  const _Float16* Wt = Wtb + (size_t)blockIdx.y * 16384;
  _Float16* out = outb + (size_t)blockIdx.y * 1048576;
  {
    const int row = tid >> 4, c = (tid & 15) * 8;
    *(half8*)&Al[row][c] = *(const half8*)(hbuf + (size_t)(i0 + row) * 128 + c);
  }
  {
    const int n = tid >> 1, h0 = (tid & 1) * 64;
    const _Float16* wp = Wt + (size_t)n * 128 + h0;
#pragma unroll
    for (int e = 0; e < 8; ++e)
      *(half8*)&Bl[n][h0 + e * 8] = *(const half8*)(wp + e * 8);
  }
  __syncthreads();
  const int fr = lane & 15, kg = (lane >> 4) * 8;
  f32x4 acc[2] = {};
#pragma unroll
  for (int kk = 0; kk < 4; ++kk) {
    half8 a   = *(const half8*)&Al[fr][kk * 32 + kg];
    half8 b0  = *(const half8*)&Bl[wv * 32 + fr][kk * 32 + kg];
    half8 b1v = *(const half8*)&Bl[wv * 32 + 16 + fr][kk * 32 + kg];
    acc[0] = MFMAH(a, b0,  acc[0]);
    acc[1] = MFMAH(a, b1v, acc[1]);
  }
#pragma unroll
  for (int n2 = 0; n2 < 2; ++n2)
#pragma unroll
    for (int r = 0; r < 4; ++r) {
      const int row = i0 + (lane >> 4) * 4 + r;
      const int col = wv * 32 + n2 * 16 + fr;
      out[(size_t)row * 128 + col] = (_Float16)acc[n2][r];
    }
}

// ---------------------------------------------------------------------------
// Attention via MFMA. Block = 16 q-rows of one batch; 4 waves; grid 512.
// Zero K-rows outside sequence -> score 0 (included), matching reference.
// ---------------------------------------------------------------------------
__global__ __launch_bounds__(256) void k_attn(const _Float16* __restrict__ Qg,
                                              const _Float16* __restrict__ Kg,
                                              const _Float16* __restrict__ Vg,
                                              const float* __restrict__ Wo,
                                              const float* __restrict__ bo,
                                              float* __restrict__ outp,
                                              float* __restrict__ attwg) {
  __shared__ _Float16 Qs[16][136];
  __shared__ _Float16 Ks[80][136];
  __shared__ _Float16 Vs[96][136];
  __shared__ _Float16 Ps[16][104];
  __shared__ float sc[16][84];
  __shared__ float aw[16 * 65];
  __shared__ float wol[128][2];
  __shared__ float proj[4][16][2];
  const int tid = threadIdx.x;
  const int lane = tid & 63, wv = tid >> 6;
  const int b = blockIdx.x >> 7;
  const int i0 = (blockIdx.x & 127) << 4;
  const int rowbase = b * 2048 + i0;
  const float invscale = 0.08838834764831845f;  // 1/sqrt(128)

  {
    const int row = tid >> 4, d8 = (tid & 15) * 8;
    *(half8*)&Qs[row][d8] = *(const half8*)(Qg + (size_t)(rowbase + row) * 128 + d8);
  }
#pragma unroll
  for (int it = 0; it < 5; ++it) {
    const int idx = it * 256 + tid;
    const int lr = idx >> 4, d8 = (idx & 15) * 8;
    const int j = i0 - 32 + lr;
    half8 kv = {0, 0, 0, 0, 0, 0, 0, 0};
    if (j >= 0 && j < 2048)
      kv = *(const half8*)(Kg + (size_t)(b * 2048 + j) * 128 + d8);
    *(half8*)&Ks[lr][d8] = kv;
  }
#pragma unroll
  for (int it = 0; it < 6; ++it) {
    const int idx = it * 256 + tid;
    const int lr = idx >> 4, d8 = (idx & 15) * 8;
    const int j = i0 - 32 + lr;
    half8 vv = {0, 0, 0, 0, 0, 0, 0, 0};
    if (lr < 80 && j >= 0 && j < 2048)
      vv = *(const half8*)(Vg + (size_t)(b * 2048 + j) * 128 + d8);
    *(half8*)&Vs[lr][d8] = vv;
  }
  wol[tid >> 1][tid & 1] = Wo[tid];
  __syncthreads();

  const int fr = lane & 15, kg8 = (lane >> 4) * 8;
  // QK^T: C[16 q][80 k] = 5 col-tiles
  {
    const int nct = (wv == 0) ? 2 : 1;
    for (int p = 0; p < nct; ++p) {
      const int ct = (p == 0) ? wv : 4;
      f32x4 acc = {};
#pragma unroll
      for (int kk = 0; kk < 4; ++kk) {
        half8 a  = *(const half8*)&Qs[fr][kk * 32 + kg8];
        half8 bb = *(const half8*)&Ks[ct * 16 + fr][kk * 32 + kg8];
        acc = MFMAH(a, bb, acc);
      }
#pragma unroll
      for (int r = 0; r < 4; ++r)
        sc[(lane >> 4) * 4 + r][ct * 16 + fr] = acc[r] * invscale;
    }
  }
  __syncthreads();

  // banded softmax; wave wv owns q-rows 4wv..4wv+3
#pragma unroll 1
  for (int rr = 0; rr < 4; ++rr) {
    const int r = wv * 4 + rr;
    const int c0 = lane;
    const bool ib0 = (c0 >= r);
    const bool ib1 = (lane <= r);
    float a0 = ib0 ? sc[r][c0] : -1e30f;
    float a1 = ib1 ? sc[r][64 + lane] : -1e30f;
    float mx = fmaxf(a0, a1);
#pragma unroll
    for (int o = 1; o < 64; o <<= 1) mx = fmaxf(mx, __shfl_xor(mx, o));
    float e0 = ib0 ? __expf(a0 - mx) : 0.f;
    float e1 = ib1 ? __expf(a1 - mx) : 0.f;
    float sm = e0 + e1;
#pragma unroll
    for (int o = 1; o < 64; o <<= 1) sm += __shfl_xor(sm, o);
    const float inv = 1.0f / sm;
    const float w0 = e0 * inv, w1 = e1 * inv;
    if (ib0) aw[r * 65 + (r + 64 - c0)] = w0;
    if (ib1) aw[r * 65 + (r - lane)] = w1;
    Ps[r][c0] = (_Float16)w0;
    if (lane < 32) Ps[r][64 + lane] = (_Float16)((lane < 16) ? w1 : 0.f);
  }
  __syncthreads();

  for (int i = tid; i < 1040; i += 256)
    attwg[(size_t)rowbase * 65 + i] = aw[i];

  // PV: C2[16 q][128 d] = P(16x96) @ V(96x128)
  f32x4 c2[2] = {};
#pragma unroll
  for (int kk = 0; kk < 3; ++kk) {
    half8 a = *(const half8*)&Ps[fr][kk * 32 + kg8];
#pragma unroll
    for (int dt2 = 0; dt2 < 2; ++dt2) {
      const int d = (2 * wv + dt2) * 16 + fr;
      half8 bb;
#pragma unroll
      for (int e = 0; e < 8; ++e) bb[e] = Vs[kk * 32 + kg8 + e][d];
      c2[dt2] = MFMAH(a, bb, c2[dt2]);
    }
  }
  // projection
#pragma unroll
  for (int r = 0; r < 4; ++r) {
    float p0 = 0.f, p1 = 0.f;
#pragma unroll
    for (int dt2 = 0; dt2 < 2; ++dt2) {
      const int d = (2 * wv + dt2) * 16 + fr;
      p0 += c2[dt2][r] * wol[d][0];
      p1 += c2[dt2][r] * wol[d][1];
    }
    p0 += __shfl_xor(p0, 1); p0 += __shfl_xor(p0, 2);
    p0 += __shfl_xor(p0, 4); p0 += __shfl_xor(p0, 8);
    p1 += __shfl_xor(p1, 1); p1 += __shfl_xor(p1, 2);
    p1 += __shfl_xor(p1, 4); p1 += __shfl_xor(p1, 8);
    if (fr == 0) {
      const int q = (lane >> 4) * 4 + r;
      proj[wv][q][0] = p0;
      proj[wv][q][1] = p1;
    }
  }
  __syncthreads();
  if (tid < 16) {
    float s0 = proj[0][tid][0] + proj[1][tid][0] + proj[2][tid][0] + proj[3][tid][0];
    float s1 = proj[0][tid][1] + proj[1][tid][1] + proj[2][tid][1] + proj[3][tid][1];
    outp[((size_t)rowbase + tid) * 2 + 0] = s0 * invscale + bo[0];
    outp[((size_t)rowbase + tid) * 2 + 1] = s1 * invscale + bo[1];
  }
}

extern "C" void kernel_launch(void* const* d_in, const int* in_sizes, int n_in,
                              void* d_out, int out_size, void* d_ws, size_t ws_size,
                              hipStream_t stream) {
  const float* x  = (const float*)d_in[0];
  const float* W1 = (const float*)d_in[1];
  const float* b1 = (const float*)d_in[2];
  const float* Wq = (const float*)d_in[3];
  const float* Wk = (const float*)d_in[4];
  const float* Wv = (const float*)d_in[5];
  const float* Wo = (const float*)d_in[6];
  const float* bo = (const float*)d_in[7];
  float* out  = (float*)d_out;            // (4,2048,2)
  float* attw = out + 16384;              // (4,2048,65)

  _Float16* W1t  = (_Float16*)d_ws;       // 128x2048
  _Float16* Wqkv = W1t + 262144;          // 3 x 128x128
  _Float16* Pe   = Wqkv + 49152;          // 2048x2048 pos-enc table
  _Float16* hbuf = Pe + 4194304;          // 8192x128
  _Float16* Qg   = hbuf + 1048576;        // 8192x128
  _Float16* Kg   = Qg + 1048576;
  _Float16* Vg   = Kg + 1048576;

  k_prep<<<1280, 256, 0, stream>>>(W1, Wq, Wk, Wv, W1t, Wqkv, Pe);
  k_gemm1<<<512, 512, 0, stream>>>(x, W1t, Pe, b1, hbuf);
  k_qkv<<<dim3(512, 3), 256, 0, stream>>>(hbuf, Wqkv, Qg);
  k_attn<<<512, 256, 0, stream>>>(Qg, Kg, Vg, Wo, bo, out, attw);
}